// Round 2
// baseline (1111.328 us; speedup 1.0000x reference)
//
#include <hip/hip_runtime.h>
#include <hip/hip_bf16.h>
#include <math.h>

#define MDIM 32768
#define NDIM 2048
#define KDIM 2048

typedef __attribute__((ext_vector_type(8))) short bf16x8;
typedef __attribute__((ext_vector_type(4))) float f32x4;

__device__ __forceinline__ unsigned short f2bf(float f) {
  unsigned int u = __float_as_uint(f);
  u += 0x7FFFu + ((u >> 16) & 1u);
  return (unsigned short)(u >> 16);
}
__device__ __forceinline__ float bf2f(unsigned short b) {
  return __uint_as_float(((unsigned int)b) << 16);
}

__device__ __forceinline__ void gll16(const void* g, void* l) {
  __builtin_amdgcn_global_load_lds((__attribute__((address_space(1))) void*)g,
                                   (__attribute__((address_space(3))) void*)l,
                                   16, 0, 0);
}

// ---------------- split x into bf16 hi/lo ----------------
__global__ void split_x_kernel(const float4* __restrict__ x, ushort4* __restrict__ xhi,
                               ushort4* __restrict__ xlo, int n4) {
  int stride = gridDim.x * blockDim.x;
  for (int i = blockIdx.x * blockDim.x + threadIdx.x; i < n4; i += stride) {
    float4 v = x[i];
    ushort4 h, l;
    h.x = f2bf(v.x); l.x = f2bf(v.x - bf2f(h.x));
    h.y = f2bf(v.y); l.y = f2bf(v.y - bf2f(h.y));
    h.z = f2bf(v.z); l.z = f2bf(v.z - bf2f(h.z));
    h.w = f2bf(v.w); l.w = f2bf(v.w - bf2f(h.w));
    xhi[i] = h; xlo[i] = l;
  }
}

// ---------------- transpose + split W1 -> WT (N x K) hi/lo ----------------
__global__ void split_wT_kernel(const float* __restrict__ w1, unsigned short* __restrict__ wthi,
                                unsigned short* __restrict__ wtlo) {
  __shared__ float tile[32][33];
  int bx = blockIdx.x, by = blockIdx.y;    // bx: h-tile, by: d-tile
  int tx = threadIdx.x, ty = threadIdx.y;  // (32, 8)
#pragma unroll
  for (int r = 0; r < 4; ++r) {
    int d = by * 32 + ty + r * 8;
    tile[ty + r * 8][tx] = w1[(size_t)d * NDIM + bx * 32 + tx];
  }
  __syncthreads();
#pragma unroll
  for (int r = 0; r < 4; ++r) {
    int h = bx * 32 + ty + r * 8;
    float v = tile[tx][ty + r * 8];   // = w1[(by*32+tx)*N + h]
    unsigned short hi = f2bf(v);
    unsigned short lo = f2bf(v - bf2f(hi));
    size_t o = (size_t)h * KDIM + by * 32 + tx;
    wthi[o] = hi; wtlo[o] = lo;
  }
}

// ---------------- fused GEMM: logits partials ----------------
// logits[m] = sum_n relu(sum_k x[m,k] W1[k,n] + b1[n]) * W2[n]
// 3-product bf16 split. 128x128 tile, BK=32, 4 waves, double-buffered LDS,
// one barrier per K-step, XOR-swizzled LDS (both-sides: pre-swizzled gll16
// source + swizzled ds_read).
//
// LDS row layout (per tile row, 128 B): chunks 0..3 = hi (K 0..31),
// chunks 4..7 = lo (K 0..31), each chunk 16 B. Swizzle: chunk ^= (row&7).
__global__ __launch_bounds__(256, 2) void gemm_fused(
    const unsigned short* __restrict__ xhi, const unsigned short* __restrict__ xlo,
    const unsigned short* __restrict__ wthi, const unsigned short* __restrict__ wtlo,
    const float* __restrict__ b1, const float* __restrict__ w2,
    float* __restrict__ part) {
  __shared__ short As[2][128 * 64];
  __shared__ short Bs[2][128 * 64];

  const int t = threadIdx.x;
  const int l = t & 63;
  const int w = t >> 6;
  const int wm = w >> 1, wn = w & 1;
  const int q = l >> 4, r16 = l & 15;
  const int bn = blockIdx.x, bm = blockIdx.y;
  const int m0 = bm * 128, n0 = bn * 128;

  f32x4 acc[4][4];
  f32x4 zero = {0.f, 0.f, 0.f, 0.f};
#pragma unroll
  for (int a = 0; a < 4; ++a)
#pragma unroll
    for (int b = 0; b < 4; ++b) acc[a][b] = zero;

  // precomputed per-thread staging constants
  const int srow = t >> 3;           // 0..31  (row within 32-row group per i)
  const int sc   = t & 7;            // chunk 0..7

#define STAGE(buf, kt)                                                         \
  {                                                                            \
    const int k0_ = (kt) * 32;                                                 \
    _Pragma("unroll")                                                          \
    for (int i = 0; i < 4; ++i) {                                              \
      int row = i * 32 + srow;                                                 \
      int cp = sc ^ (row & 7);                                                 \
      int koff = (cp & 3) << 4;                                                \
      size_t abyte = ((size_t)(m0 + row) * KDIM + k0_) * 2 + koff;             \
      size_t bbyte = ((size_t)(n0 + row) * KDIM + k0_) * 2 + koff;             \
      const char* asrc = (cp < 4 ? (const char*)xhi : (const char*)xlo) + abyte; \
      const char* bsrc = (cp < 4 ? (const char*)wthi : (const char*)wtlo) + bbyte; \
      int dst = (i * 256 + t) * 16;                                            \
      gll16(asrc, (char*)As[buf] + dst);                                       \
      gll16(bsrc, (char*)Bs[buf] + dst);                                       \
    }                                                                          \
  }

#define COMPUTE(buf)                                                           \
  {                                                                            \
    bf16x8 ah[4], al[4], bh[4], bl[4];                                         \
    const int khi = q << 4;                                                    \
    _Pragma("unroll")                                                          \
    for (int f = 0; f < 4; ++f) {                                              \
      int ar = wm * 64 + f * 16 + r16;                                         \
      int br = wn * 64 + f * 16 + r16;                                         \
      int asw = (ar & 7) << 4, bsw = (br & 7) << 4;                            \
      const char* ap = (const char*)As[buf] + ar * 128;                        \
      const char* bp = (const char*)Bs[buf] + br * 128;                        \
      ah[f] = *(const bf16x8*)(ap + (khi ^ asw));                              \
      al[f] = *(const bf16x8*)(ap + ((64 + khi) ^ asw));                       \
      bh[f] = *(const bf16x8*)(bp + (khi ^ bsw));                              \
      bl[f] = *(const bf16x8*)(bp + ((64 + khi) ^ bsw));                       \
    }                                                                          \
    __builtin_amdgcn_s_setprio(1);                                             \
    _Pragma("unroll")                                                          \
    for (int fm = 0; fm < 4; ++fm)                                             \
      _Pragma("unroll")                                                        \
      for (int fn = 0; fn < 4; ++fn) {                                         \
        acc[fm][fn] = __builtin_amdgcn_mfma_f32_16x16x32_bf16(ah[fm], bh[fn], acc[fm][fn], 0, 0, 0); \
        acc[fm][fn] = __builtin_amdgcn_mfma_f32_16x16x32_bf16(ah[fm], bl[fn], acc[fm][fn], 0, 0, 0); \
        acc[fm][fn] = __builtin_amdgcn_mfma_f32_16x16x32_bf16(al[fm], bh[fn], acc[fm][fn], 0, 0, 0); \
      }                                                                        \
    __builtin_amdgcn_s_setprio(0);                                             \
  }

  STAGE(0, 0);
  __syncthreads();   // compiler emits vmcnt(0) drain before barrier
  for (int kt = 0; kt < KDIM / 32; ++kt) {
    if (kt < KDIM / 32 - 1) STAGE((kt + 1) & 1, kt + 1);
    COMPUTE(kt & 1);
    __syncthreads(); // staged buf ready for all; compute buf free to overwrite
  }

  // epilogue: relu(acc + b1) * w2, reduce over columns
  float b1v[4], w2v[4];
#pragma unroll
  for (int fn = 0; fn < 4; ++fn) {
    int n = n0 + wn * 64 + fn * 16 + r16;
    b1v[fn] = b1[n];
    w2v[fn] = w2[n];
  }

  float val[4][4];
#pragma unroll
  for (int fm = 0; fm < 4; ++fm)
#pragma unroll
    for (int j = 0; j < 4; ++j) {
      float s = 0.f;
#pragma unroll
      for (int fn = 0; fn < 4; ++fn) {
        float h = acc[fm][fn][j] + b1v[fn];
        h = fmaxf(h, 0.f);
        s += h * w2v[fn];
      }
      // C/D layout: col = lane&15, row = (lane>>4)*4 + j  -> reduce over the 16 cols
      s += __shfl_xor(s, 1);
      s += __shfl_xor(s, 2);
      s += __shfl_xor(s, 4);
      s += __shfl_xor(s, 8);
      val[fm][j] = s;
    }

  float* red = (float*)As[0];      // 256 floats (LDS free after final barrier)
  if (r16 == 0) {
#pragma unroll
    for (int fm = 0; fm < 4; ++fm)
#pragma unroll
      for (int j = 0; j < 4; ++j)
        red[wn * 128 + wm * 64 + fm * 16 + q * 4 + j] = val[fm][j];
  }
  __syncthreads();
  if (t < 128) {
    float p = red[t] + red[128 + t];
    part[(size_t)(m0 + t) * 16 + bn] = p;   // deterministic per-N-tile partial
  }
#undef STAGE
#undef COMPUTE
}

// ---------------- reduce partials -> logits ----------------
__global__ void reduce_part(const float* __restrict__ part, const float* __restrict__ b2,
                            float* __restrict__ logits) {
  int m = blockIdx.x * blockDim.x + threadIdx.x;
  if (m >= MDIM) return;
  float s = 0.f;
#pragma unroll
  for (int i = 0; i < 16; ++i) s += part[(size_t)m * 16 + i];
  logits[m] = s + b2[0];
}

// ---------------- per-batch-row: expected_k, top-k mask ----------------
__global__ void rowstats(const float* __restrict__ logits, float* __restrict__ mask_out,
                         float* __restrict__ ek_out) {
  __shared__ float vals[2048];
  __shared__ float srt[2048];
  __shared__ float redf[256];
  __shared__ int redi[256];
  int b = blockIdx.x, t = threadIdx.x;
  const float* row = logits + (size_t)b * 2048;
  float psum = 0.f;
  for (int i = t; i < 2048; i += 256) {
    float v = row[i];
    vals[i] = v; srt[i] = v;
    psum += 1.f / (1.f + expf(-v));
  }
  redf[t] = psum;
  __syncthreads();
  for (int s = 128; s > 0; s >>= 1) {
    if (t < s) redf[t] += redf[t + s];
    __syncthreads();
  }
  float ek = redf[0];
  int k = (int)ek;          // truncation toward zero, matches astype(int32)
  if (k < 32) k = 32;
  if (k > 2048) k = 2048;
  if (t == 0) ek_out[b] = ek;

  // bitonic sort ascending
  for (int ksz = 2; ksz <= 2048; ksz <<= 1) {
    for (int j = ksz >> 1; j > 0; j >>= 1) {
      for (int i = t; i < 2048; i += 256) {
        int ixj = i ^ j;
        if (ixj > i) {
          float a = srt[i], c = srt[ixj];
          bool up = ((i & ksz) == 0);
          if ((a > c) == up) { srt[i] = c; srt[ixj] = a; }
        }
      }
      __syncthreads();
    }
  }
  float thr = srt[2048 - k];   // k-th largest

  int cnt = 0;
  for (int i = t; i < 2048; i += 256) cnt += (vals[i] > thr) ? 1 : 0;
  redi[t] = cnt;
  __syncthreads();
  for (int s = 128; s > 0; s >>= 1) {
    if (t < s) redi[t] += redi[t + s];
    __syncthreads();
  }
  int n_gt = redi[0];
  int need = k - n_gt;   // #ties to admit, by smallest index (stable argsort)

  for (int i = t; i < 2048; i += 256) {
    float v = vals[i];
    float m = 0.f;
    if (v > thr) m = 1.f;
    else if (v == thr) {
      int pre = 0;
      for (int p = 0; p < i; ++p) pre += (vals[p] == thr) ? 1 : 0;
      if (pre < need) m = 1.f;
    }
    mask_out[(size_t)b * 2048 + i] = m;
  }
}

// ---------------- filtered = x * mask ----------------
__global__ void filter_k(const float4* __restrict__ x, const float* __restrict__ mask,
                         float4* __restrict__ out, int n4) {
  int stride = gridDim.x * blockDim.x;
  for (int i = blockIdx.x * blockDim.x + threadIdx.x; i < n4; i += stride) {
    float m = mask[i >> 9];   // 512 float4 per row (D=2048)
    float4 v = x[i];
    v.x *= m; v.y *= m; v.z *= m; v.w *= m;
    out[i] = v;
  }
}

extern "C" void kernel_launch(void* const* d_in, const int* in_sizes, int n_in,
                              void* d_out, int out_size, void* d_ws, size_t ws_size,
                              hipStream_t stream) {
  const float* x  = (const float*)d_in[0];   // [16,2048,2048]
  const float* w1 = (const float*)d_in[1];   // [2048,2048]
  const float* b1 = (const float*)d_in[2];   // [2048]
  const float* w2 = (const float*)d_in[3];   // [2048,1]
  const float* b2 = (const float*)d_in[4];   // [1]

  float* out_filt = (float*)d_out;                         // 67108864 floats
  float* out_mask = out_filt + (size_t)67108864;           // 32768
  float* out_ek   = out_mask + 32768;                      // 16

  // x_hi parked in out0 region (268 MB >= 134 MB), overwritten by filter at the end
  unsigned short* xhi = (unsigned short*)d_out;

  char* wsb = (char*)d_ws;
  unsigned short* xlo  = (unsigned short*)wsb;                      // 134217728 B
  unsigned short* wthi = (unsigned short*)(wsb + 134217728);        // 8388608 B
  unsigned short* wtlo = (unsigned short*)(wsb + 142606336);        // 8388608 B
  float* part   = (float*)(wsb + 150994944);                        // 2097152 B
  float* logits = (float*)(wsb + 153092096);                        // 131072 B

  split_x_kernel<<<dim3(4096), dim3(256), 0, stream>>>(
      (const float4*)x, (ushort4*)xhi, (ushort4*)xlo, 16777216);
  split_wT_kernel<<<dim3(64, 64), dim3(32, 8), 0, stream>>>(w1, wthi, wtlo);
  gemm_fused<<<dim3(16, 256), dim3(256), 0, stream>>>(
      xhi, xlo, wthi, wtlo, b1, w2, part);
  reduce_part<<<dim3(128), dim3(256), 0, stream>>>(part, b2, logits);
  rowstats<<<dim3(16), dim3(256), 0, stream>>>(logits, out_mask, out_ek);
  filter_k<<<dim3(4096), dim3(256), 0, stream>>>(
      (const float4*)x, out_mask, (float4*)out_filt, 16777216);
}

// Round 3
// 973.598 us; speedup vs baseline: 1.1415x; 1.1415x over previous
//
#include <hip/hip_runtime.h>
#include <hip/hip_bf16.h>
#include <math.h>

#define MDIM 32768
#define NDIM 2048
#define KDIM 2048

typedef __attribute__((ext_vector_type(8))) short bf16x8;
typedef __attribute__((ext_vector_type(4))) float f32x4;

__device__ __forceinline__ unsigned short f2bf(float f) {
  unsigned int u = __float_as_uint(f);
  u += 0x7FFFu + ((u >> 16) & 1u);
  return (unsigned short)(u >> 16);
}
__device__ __forceinline__ float bf2f(unsigned short b) {
  return __uint_as_float(((unsigned int)b) << 16);
}

__device__ __forceinline__ void gll16(const void* g, void* l) {
  __builtin_amdgcn_global_load_lds((__attribute__((address_space(1))) void*)g,
                                   (__attribute__((address_space(3))) void*)l,
                                   16, 0, 0);
}

// ---------------- split x into bf16 hi/lo ----------------
__global__ void split_x_kernel(const float4* __restrict__ x, ushort4* __restrict__ xhi,
                               ushort4* __restrict__ xlo, int n4) {
  int stride = gridDim.x * blockDim.x;
  for (int i = blockIdx.x * blockDim.x + threadIdx.x; i < n4; i += stride) {
    float4 v = x[i];
    ushort4 h, l;
    h.x = f2bf(v.x); l.x = f2bf(v.x - bf2f(h.x));
    h.y = f2bf(v.y); l.y = f2bf(v.y - bf2f(h.y));
    h.z = f2bf(v.z); l.z = f2bf(v.z - bf2f(h.z));
    h.w = f2bf(v.w); l.w = f2bf(v.w - bf2f(h.w));
    xhi[i] = h; xlo[i] = l;
  }
}

// ---------------- transpose + split W1 -> WT (N x K) hi/lo ----------------
__global__ void split_wT_kernel(const float* __restrict__ w1, unsigned short* __restrict__ wthi,
                                unsigned short* __restrict__ wtlo) {
  __shared__ float tile[32][33];
  int bx = blockIdx.x, by = blockIdx.y;
  int tx = threadIdx.x, ty = threadIdx.y;  // (32, 8)
#pragma unroll
  for (int r = 0; r < 4; ++r) {
    int d = by * 32 + ty + r * 8;
    tile[ty + r * 8][tx] = w1[(size_t)d * NDIM + bx * 32 + tx];
  }
  __syncthreads();
#pragma unroll
  for (int r = 0; r < 4; ++r) {
    int h = bx * 32 + ty + r * 8;
    float v = tile[tx][ty + r * 8];
    unsigned short hi = f2bf(v);
    unsigned short lo = f2bf(v - bf2f(hi));
    size_t o = (size_t)h * KDIM + by * 32 + tx;
    wthi[o] = hi; wtlo[o] = lo;
  }
}

// ---------------- fused 8-phase GEMM ----------------
// logits[m] = sum_n relu(sum_k x[m,k] W1[k,n] + b1[n]) * W2[n]
// 3-product split folded into K' = 96 K-tiles of 64:
//   kt  0..31: xhi * wthi ; 32..63: xhi * wtlo ; 64..95: xlo * wthi
// BM=BN=256, BK=64, 8 waves (512 thr). LDS = ring of 8 half-tile slots
// (16 KB each, 128 rows x 64 k bf16, XOR-swizzled). Half-tile stream per
// tile: [A0,B0,B1,A1]. 4 phases/tile = C-quadrants Q00,Q01,Q11,Q10,
// 16 MFMA each. Stage lead = 5 half-tiles, per-phase vmcnt(6) (counted,
// never 0 in the loop) + raw s_barrier.
__global__ __launch_bounds__(512, 2) void gemm8(
    const unsigned short* __restrict__ xhi, const unsigned short* __restrict__ xlo,
    const unsigned short* __restrict__ wthi, const unsigned short* __restrict__ wtlo,
    const float* __restrict__ b1, const float* __restrict__ w2,
    float* __restrict__ part) {
  __shared__ char lds[8 * 16384];   // 128 KiB ring

  const int t = threadIdx.x;
  const int l = t & 63;
  const int w = t >> 6;
  const int sub_m = w >> 2, sub_n = w & 3;
  const int r16 = l & 15;
  const int q4 = l >> 4;

  // XCD-chunked bijective swizzle: 1024 blocks = 8 XCDs x 128
  int bid = blockIdx.x;
  int id = (bid & 7) * 128 + (bid >> 3);
  const int bm = id >> 3, bn = id & 7;
  const int m0 = bm * 256, n0 = bn * 256;

  // staging per-thread constants
  const int tr = t >> 3;                                  // 0..63
  const int cs16 = (((t & 7) ^ ((t >> 3) & 7)) << 4);     // swizzled chunk byte
  const int t16 = t << 4;

  // read-side per-thread constants
  const int axor = (l & 7) << 4;
  const int akoff = ((l >> 4) & 3) << 4;
  const int a_row0 = sub_m * 64 + (l & 15);
  const int b_row0 = sub_n * 32 + (l & 15);

#define STAGE(nn)                                                              \
  {                                                                            \
    int n_ = (nn);                                                             \
    if (n_ < 384) {                                                            \
      int jt = n_ >> 2, pos = n_ & 3;                                          \
      bool isA = (pos == 0) || (pos == 3);                                     \
      int hh = (pos >= 2) ? 1 : 0;                                             \
      const unsigned short* base =                                             \
          isA ? ((jt < 64) ? xhi : xlo)                                        \
              : ((jt < 32 || jt >= 64) ? wthi : wtlo);                         \
      int k0 = (jt & 31) << 6;                                                 \
      int row0 = (isA ? m0 : n0) + (hh << 7);                                  \
      char* dst = lds + ((n_ & 7) << 14) + t16;                                \
      const char* src = (const char*)base +                                    \
          ((((size_t)(row0 + tr)) << 11) + (size_t)k0) * 2 + cs16;             \
      gll16(src, dst);                                                         \
      gll16(src + (64ull << 12), dst + 8192);                                  \
    }                                                                          \
  }

#define LDA(slot)                                                              \
  _Pragma("unroll")                                                            \
  for (int fm = 0; fm < 4; ++fm)                                               \
    _Pragma("unroll")                                                          \
    for (int kk = 0; kk < 2; ++kk)                                             \
      a[fm][kk] = *(const bf16x8*)(lds + ((slot) << 14) +                      \
          (a_row0 + fm * 16) * 128 + (((kk << 6) | akoff) ^ axor));

#define LDB(dst, slot)                                                         \
  _Pragma("unroll")                                                            \
  for (int fn = 0; fn < 2; ++fn)                                               \
    _Pragma("unroll")                                                          \
    for (int kk = 0; kk < 2; ++kk)                                             \
      dst[fn][kk] = *(const bf16x8*)(lds + ((slot) << 14) +                    \
          (b_row0 + fn * 16) * 128 + (((kk << 6) | akoff) ^ axor));

#define MFMA16(accq, bb)                                                       \
  __builtin_amdgcn_s_setprio(1);                                               \
  _Pragma("unroll")                                                            \
  for (int fm = 0; fm < 4; ++fm)                                               \
    _Pragma("unroll")                                                          \
    for (int fn = 0; fn < 2; ++fn) {                                           \
      accq[fm][fn] = __builtin_amdgcn_mfma_f32_16x16x32_bf16(a[fm][0], bb[fn][0], accq[fm][fn], 0, 0, 0); \
      accq[fm][fn] = __builtin_amdgcn_mfma_f32_16x16x32_bf16(a[fm][1], bb[fn][1], accq[fm][fn], 0, 0, 0); \
    }                                                                          \
  __builtin_amdgcn_s_setprio(0);

#define WAITBAR                                                                \
  asm volatile("s_waitcnt vmcnt(6)" ::: "memory");                             \
  __builtin_amdgcn_s_barrier();                                                \
  asm volatile("" ::: "memory");

  f32x4 acc00[4][2], acc01[4][2], acc11[4][2], acc10[4][2];
  f32x4 zero = {0.f, 0.f, 0.f, 0.f};
#pragma unroll
  for (int i = 0; i < 4; ++i)
#pragma unroll
    for (int j = 0; j < 2; ++j) {
      acc00[i][j] = zero; acc01[i][j] = zero;
      acc11[i][j] = zero; acc10[i][j] = zero;
    }

  bf16x8 a[4][2], b0[2][2], b1f[2][2];

  // prologue: stage H(0..4), require H0,H1 landed (3 half-tiles in flight)
  STAGE(0); STAGE(1); STAGE(2); STAGE(3); STAGE(4);
  asm volatile("s_waitcnt vmcnt(6)" ::: "memory");
  __builtin_amdgcn_s_barrier();
  asm volatile("" ::: "memory");

  for (int kt = 0; kt < 96; ++kt) {
    const int sb = (kt & 1) << 2;     // slot base: 0 or 4
    const int nb = 4 * kt;
    // phase 0: Q00 — read A0 (slot sb), B0 (slot sb+1)
    STAGE(nb + 5);
    LDA(sb);
    LDB(b0, sb + 1);
    MFMA16(acc00, b0);
    WAITBAR;
    // phase 1: Q01 — reuse A0, read B1 (slot sb+2)
    STAGE(nb + 6);
    LDB(b1f, sb + 2);
    MFMA16(acc01, b1f);
    WAITBAR;
    // phase 2: Q11 — read A1 (slot sb+3), reuse B1
    STAGE(nb + 7);
    LDA(sb + 3);
    MFMA16(acc11, b1f);
    WAITBAR;
    // phase 3: Q10 — reuse A1, reuse B0
    STAGE(nb + 8);
    MFMA16(acc10, b0);
    WAITBAR;
  }

  // drain all staging before reusing LDS
  asm volatile("s_waitcnt vmcnt(0)" ::: "memory");
  __builtin_amdgcn_s_barrier();
  asm volatile("" ::: "memory");

  // epilogue: relu(acc + b1) * w2, reduce over n
  float b1v[2][2], w2v[2][2];
#pragma unroll
  for (int nh = 0; nh < 2; ++nh)
#pragma unroll
    for (int fn = 0; fn < 2; ++fn) {
      int n = n0 + nh * 128 + sub_n * 32 + fn * 16 + r16;
      b1v[nh][fn] = b1[n];
      w2v[nh][fn] = w2[n];
    }

  float* red = (float*)lds;   // 4 x 256 floats
#pragma unroll
  for (int mh = 0; mh < 2; ++mh)
#pragma unroll
    for (int fm = 0; fm < 4; ++fm)
#pragma unroll
      for (int j = 0; j < 4; ++j) {
        float s = 0.f;
#pragma unroll
        for (int fn = 0; fn < 2; ++fn) {
          float h0 = (mh == 0 ? acc00[fm][fn][j] : acc10[fm][fn][j]) + b1v[0][fn];
          s += fmaxf(h0, 0.f) * w2v[0][fn];
          float h1 = (mh == 0 ? acc01[fm][fn][j] : acc11[fm][fn][j]) + b1v[1][fn];
          s += fmaxf(h1, 0.f) * w2v[1][fn];
        }
        s += __shfl_xor(s, 1);
        s += __shfl_xor(s, 2);
        s += __shfl_xor(s, 4);
        s += __shfl_xor(s, 8);
        if (r16 == 0)
          red[sub_n * 256 + mh * 128 + sub_m * 64 + fm * 16 + q4 * 4 + j] = s;
      }
  __syncthreads();
  if (t < 256) {
    float p = red[t] + red[256 + t] + red[512 + t] + red[768 + t];
    part[(size_t)(m0 + t) * 8 + bn] = p;
  }
#undef STAGE
#undef LDA
#undef LDB
#undef MFMA16
#undef WAITBAR
}

// ---------------- reduce partials -> logits ----------------
__global__ void reduce_part(const float* __restrict__ part, const float* __restrict__ b2,
                            float* __restrict__ logits) {
  int m = blockIdx.x * blockDim.x + threadIdx.x;
  if (m >= MDIM) return;
  float s = 0.f;
#pragma unroll
  for (int i = 0; i < 8; ++i) s += part[(size_t)m * 8 + i];
  logits[m] = s + b2[0];
}

// ---------------- per-batch-row: expected_k, top-k mask ----------------
__global__ void rowstats(const float* __restrict__ logits, float* __restrict__ mask_out,
                         float* __restrict__ ek_out) {
  __shared__ float vals[2048];
  __shared__ float srt[2048];
  __shared__ float redf[256];
  __shared__ int redi[256];
  int b = blockIdx.x, t = threadIdx.x;
  const float* row = logits + (size_t)b * 2048;
  float psum = 0.f;
  for (int i = t; i < 2048; i += 256) {
    float v = row[i];
    vals[i] = v; srt[i] = v;
    psum += 1.f / (1.f + expf(-v));
  }
  redf[t] = psum;
  __syncthreads();
  for (int s = 128; s > 0; s >>= 1) {
    if (t < s) redf[t] += redf[t + s];
    __syncthreads();
  }
  float ek = redf[0];
  int k = (int)ek;
  if (k < 32) k = 32;
  if (k > 2048) k = 2048;
  if (t == 0) ek_out[b] = ek;

  for (int ksz = 2; ksz <= 2048; ksz <<= 1) {
    for (int j = ksz >> 1; j > 0; j >>= 1) {
      for (int i = t; i < 2048; i += 256) {
        int ixj = i ^ j;
        if (ixj > i) {
          float a = srt[i], c = srt[ixj];
          bool up = ((i & ksz) == 0);
          if ((a > c) == up) { srt[i] = c; srt[ixj] = a; }
        }
      }
      __syncthreads();
    }
  }
  float thr = srt[2048 - k];

  int cnt = 0;
  for (int i = t; i < 2048; i += 256) cnt += (vals[i] > thr) ? 1 : 0;
  redi[t] = cnt;
  __syncthreads();
  for (int s = 128; s > 0; s >>= 1) {
    if (t < s) redi[t] += redi[t + s];
    __syncthreads();
  }
  int n_gt = redi[0];
  int need = k - n_gt;

  for (int i = t; i < 2048; i += 256) {
    float v = vals[i];
    float m = 0.f;
    if (v > thr) m = 1.f;
    else if (v == thr) {
      int pre = 0;
      for (int p = 0; p < i; ++p) pre += (vals[p] == thr) ? 1 : 0;
      if (pre < need) m = 1.f;
    }
    mask_out[(size_t)b * 2048 + i] = m;
  }
}

// ---------------- filtered = x * mask ----------------
__global__ void filter_k(const float4* __restrict__ x, const float* __restrict__ mask,
                         float4* __restrict__ out, int n4) {
  int stride = gridDim.x * blockDim.x;
  for (int i = blockIdx.x * blockDim.x + threadIdx.x; i < n4; i += stride) {
    float m = mask[i >> 9];
    float4 v = x[i];
    v.x *= m; v.y *= m; v.z *= m; v.w *= m;
    out[i] = v;
  }
}

extern "C" void kernel_launch(void* const* d_in, const int* in_sizes, int n_in,
                              void* d_out, int out_size, void* d_ws, size_t ws_size,
                              hipStream_t stream) {
  const float* x  = (const float*)d_in[0];
  const float* w1 = (const float*)d_in[1];
  const float* b1 = (const float*)d_in[2];
  const float* w2 = (const float*)d_in[3];
  const float* b2 = (const float*)d_in[4];

  float* out_filt = (float*)d_out;
  float* out_mask = out_filt + (size_t)67108864;
  float* out_ek   = out_mask + 32768;

  unsigned short* xhi = (unsigned short*)d_out;   // parked in out0 region

  char* wsb = (char*)d_ws;
  unsigned short* xlo  = (unsigned short*)wsb;                      // 134217728 B
  unsigned short* wthi = (unsigned short*)(wsb + 134217728);        // 8388608 B
  unsigned short* wtlo = (unsigned short*)(wsb + 142606336);        // 8388608 B
  float* part   = (float*)(wsb + 150994944);                        // 1048576 B used
  float* logits = (float*)(wsb + 153092096);                        // 131072 B

  split_x_kernel<<<dim3(4096), dim3(256), 0, stream>>>(
      (const float4*)x, (ushort4*)xhi, (ushort4*)xlo, 16777216);
  split_wT_kernel<<<dim3(64, 64), dim3(32, 8), 0, stream>>>(w1, wthi, wtlo);
  gemm8<<<dim3(1024), dim3(512), 0, stream>>>(
      xhi, xlo, wthi, wtlo, b1, w2, part);
  reduce_part<<<dim3(128), dim3(256), 0, stream>>>(part, b2, logits);
  rowstats<<<dim3(16), dim3(256), 0, stream>>>(logits, out_mask, out_ek);
  filter_k<<<dim3(4096), dim3(256), 0, stream>>>(
      (const float4*)x, out_mask, (float4*)out_filt, 16777216);
}

// Round 4
// 967.043 us; speedup vs baseline: 1.1492x; 1.0068x over previous
//
#include <hip/hip_runtime.h>
#include <hip/hip_bf16.h>
#include <math.h>

#define MDIM 32768
#define NDIM 2048
#define KDIM 2048

typedef __attribute__((ext_vector_type(8))) short bf16x8;
typedef __attribute__((ext_vector_type(4))) float f32x4;

__device__ __forceinline__ unsigned short f2bf(float f) {
  unsigned int u = __float_as_uint(f);
  u += 0x7FFFu + ((u >> 16) & 1u);
  return (unsigned short)(u >> 16);
}
__device__ __forceinline__ float bf2f(unsigned short b) {
  return __uint_as_float(((unsigned int)b) << 16);
}

__device__ __forceinline__ void gll16(const void* g, void* l) {
  __builtin_amdgcn_global_load_lds((__attribute__((address_space(1))) void*)g,
                                   (__attribute__((address_space(3))) void*)l,
                                   16, 0, 0);
}

// ---------------- split x into bf16 hi/lo ----------------
__global__ void split_x_kernel(const float4* __restrict__ x, ushort4* __restrict__ xhi,
                               ushort4* __restrict__ xlo, int n4) {
  int stride = gridDim.x * blockDim.x;
  for (int i = blockIdx.x * blockDim.x + threadIdx.x; i < n4; i += stride) {
    float4 v = x[i];
    ushort4 h, l;
    h.x = f2bf(v.x); l.x = f2bf(v.x - bf2f(h.x));
    h.y = f2bf(v.y); l.y = f2bf(v.y - bf2f(h.y));
    h.z = f2bf(v.z); l.z = f2bf(v.z - bf2f(h.z));
    h.w = f2bf(v.w); l.w = f2bf(v.w - bf2f(h.w));
    xhi[i] = h; xlo[i] = l;
  }
}

// ---------------- transpose + split W1 -> WT (N x K) hi/lo ----------------
__global__ void split_wT_kernel(const float* __restrict__ w1, unsigned short* __restrict__ wthi,
                                unsigned short* __restrict__ wtlo) {
  __shared__ float tile[32][33];
  int bx = blockIdx.x, by = blockIdx.y;
  int tx = threadIdx.x, ty = threadIdx.y;  // (32, 8)
#pragma unroll
  for (int r = 0; r < 4; ++r) {
    int d = by * 32 + ty + r * 8;
    tile[ty + r * 8][tx] = w1[(size_t)d * NDIM + bx * 32 + tx];
  }
  __syncthreads();
#pragma unroll
  for (int r = 0; r < 4; ++r) {
    int h = bx * 32 + ty + r * 8;
    float v = tile[tx][ty + r * 8];
    unsigned short hi = f2bf(v);
    unsigned short lo = f2bf(v - bf2f(hi));
    size_t o = (size_t)h * KDIM + by * 32 + tx;
    wthi[o] = hi; wtlo[o] = lo;
  }
}

// ---------------- fused 8-phase GEMM, MFMA-first phases ----------------
// logits[m] = sum_n relu(sum_k x[m,k] W1[k,n] + b1[n]) * W2[n]
// 3-product split folded into 96 K-tiles of 64:
//   kt 0..31: xhi*wthi ; 32..63: xhi*wtlo ; 64..95: xlo*wthi
// BM=BN=256, BK=64, 8 waves. LDS ring = 8 half-tile slots (16 KB, swizzled).
// Half-tile stream per tile: [A0,B0,B1,A1]. Phase order Q00,Q01,Q11,Q10 so
// operand uses are adjacent; each phase: STAGE -> MFMA (on frags read last
// phase) -> ds_read fills for next phase -> vmcnt(6) -> barrier.
// Stage lead = 7 half-tiles so fills (slot <= g+2) are landed (<= g+3).
__global__ __launch_bounds__(512, 2) void gemm8(
    const unsigned short* __restrict__ xhi, const unsigned short* __restrict__ xlo,
    const unsigned short* __restrict__ wthi, const unsigned short* __restrict__ wtlo,
    const float* __restrict__ b1, const float* __restrict__ w2,
    float* __restrict__ part) {
  __shared__ char lds[8 * 16384];   // 128 KiB ring

  const int t = threadIdx.x;
  const int l = t & 63;
  const int w = t >> 6;
  const int sub_m = w >> 2, sub_n = w & 3;
  const int r16 = l & 15;
  const int q4 = l >> 4;

  // XCD-chunked bijective swizzle: 1024 blocks = 8 XCDs x 128
  int bid = blockIdx.x;
  int id = (bid & 7) * 128 + (bid >> 3);
  const int bm = id >> 3, bn = id & 7;
  const int m0 = bm * 256, n0 = bn * 256;

  // staging per-thread constants
  const int tr = t >> 3;                                  // 0..63
  const int cs16 = (((t & 7) ^ ((t >> 3) & 7)) << 4);     // swizzled chunk byte
  const int t16 = t << 4;

  // read-side per-thread constants
  const int axor = (l & 7) << 4;
  const int akoff = ((l >> 4) & 3) << 4;
  const int a_row0 = sub_m * 64 + (l & 15);
  const int b_row0 = sub_n * 32 + (l & 15);

#define STAGE(nn)                                                              \
  {                                                                            \
    int n_ = (nn);                                                             \
    if (n_ < 384) {                                                            \
      int jt = n_ >> 2, pos = n_ & 3;                                          \
      bool isA = (pos == 0) || (pos == 3);                                     \
      int hh = (pos >= 2) ? 1 : 0;                                             \
      const unsigned short* base =                                             \
          isA ? ((jt < 64) ? xhi : xlo)                                        \
              : ((jt < 32 || jt >= 64) ? wthi : wtlo);                         \
      int k0 = (jt & 31) << 6;                                                 \
      int row0 = (isA ? m0 : n0) + (hh << 7);                                  \
      char* dst = lds + ((n_ & 7) << 14) + t16;                                \
      const char* src = (const char*)base +                                    \
          ((((size_t)(row0 + tr)) << 11) + (size_t)k0) * 2 + cs16;             \
      gll16(src, dst);                                                         \
      gll16(src + (64ull << 12), dst + 8192);                                  \
    }                                                                          \
  }

#define LDA(slot)                                                              \
  _Pragma("unroll")                                                            \
  for (int fm = 0; fm < 4; ++fm)                                               \
    _Pragma("unroll")                                                          \
    for (int kk = 0; kk < 2; ++kk)                                             \
      a[fm][kk] = *(const bf16x8*)(lds + ((slot) << 14) +                      \
          (a_row0 + fm * 16) * 128 + (((kk << 6) | akoff) ^ axor));

#define LDB(dst, slot)                                                         \
  _Pragma("unroll")                                                            \
  for (int fn = 0; fn < 2; ++fn)                                               \
    _Pragma("unroll")                                                          \
    for (int kk = 0; kk < 2; ++kk)                                             \
      dst[fn][kk] = *(const bf16x8*)(lds + ((slot) << 14) +                    \
          (b_row0 + fn * 16) * 128 + (((kk << 6) | akoff) ^ axor));

#define MFMA16(accq, bb)                                                       \
  __builtin_amdgcn_s_setprio(1);                                               \
  _Pragma("unroll")                                                            \
  for (int fm = 0; fm < 4; ++fm)                                               \
    _Pragma("unroll")                                                          \
    for (int fn = 0; fn < 2; ++fn) {                                           \
      accq[fm][fn] = __builtin_amdgcn_mfma_f32_16x16x32_bf16(a[fm][0], bb[fn][0], accq[fm][fn], 0, 0, 0); \
      accq[fm][fn] = __builtin_amdgcn_mfma_f32_16x16x32_bf16(a[fm][1], bb[fn][1], accq[fm][fn], 0, 0, 0); \
    }                                                                          \
  __builtin_amdgcn_s_setprio(0);

#define WAITBAR                                                                \
  asm volatile("s_waitcnt vmcnt(6)" ::: "memory");                             \
  __builtin_amdgcn_s_barrier();                                                \
  asm volatile("" ::: "memory");

  f32x4 acc00[4][2], acc01[4][2], acc11[4][2], acc10[4][2];
  f32x4 zero = {0.f, 0.f, 0.f, 0.f};
#pragma unroll
  for (int i = 0; i < 4; ++i)
#pragma unroll
    for (int j = 0; j < 2; ++j) {
      acc00[i][j] = zero; acc01[i][j] = zero;
      acc11[i][j] = zero; acc10[i][j] = zero;
    }

  bf16x8 a[4][2], b0f[2][2], b1f[2][2];

  // prologue: stage H0..H6 (lead 7); vmcnt(6) -> H0..H3 landed
  STAGE(0); STAGE(1); STAGE(2); STAGE(3); STAGE(4); STAGE(5); STAGE(6);
  asm volatile("s_waitcnt vmcnt(6)" ::: "memory");
  __builtin_amdgcn_s_barrier();
  asm volatile("" ::: "memory");
  LDA(0);          // A0 of tile 0
  LDB(b0f, 1);     // B0 of tile 0

  for (int kt = 0; kt < 96; ++kt) {
    const int sb = (kt & 1) << 2;
    const int g0 = 4 * kt;
    // p0: Q00 = A0 x B0 ; fill b1f <- B1 (slot sb+2)
    STAGE(g0 + 7);
    MFMA16(acc00, b0f);
    LDB(b1f, sb + 2);
    WAITBAR;
    // p1: Q01 = A0 x B1 ; fill a <- A1 (slot sb+3)
    STAGE(g0 + 8);
    MFMA16(acc01, b1f);
    LDA(sb + 3);
    WAITBAR;
    // p2: Q11 = A1 x B1 ; no fills
    STAGE(g0 + 9);
    MFMA16(acc11, b1f);
    WAITBAR;
    // p3: Q10 = A1 x B0 ; fill a <- A0' (slot (sb+4)&7), b0f <- B0' ((sb+5)&7)
    STAGE(g0 + 10);
    MFMA16(acc10, b0f);
    LDA((sb + 4) & 7);
    LDB(b0f, (sb + 5) & 7);
    WAITBAR;
  }

  // drain all staging before reusing LDS
  asm volatile("s_waitcnt vmcnt(0)" ::: "memory");
  __builtin_amdgcn_s_barrier();
  asm volatile("" ::: "memory");

  // epilogue: relu(acc + b1) * w2, reduce over n
  float b1v[2][2], w2v[2][2];
#pragma unroll
  for (int nh = 0; nh < 2; ++nh)
#pragma unroll
    for (int fn = 0; fn < 2; ++fn) {
      int n = n0 + nh * 128 + sub_n * 32 + fn * 16 + r16;
      b1v[nh][fn] = b1[n];
      w2v[nh][fn] = w2[n];
    }

  float* red = (float*)lds;   // 4 x 256 floats
#pragma unroll
  for (int mh = 0; mh < 2; ++mh)
#pragma unroll
    for (int fm = 0; fm < 4; ++fm)
#pragma unroll
      for (int j = 0; j < 4; ++j) {
        float s = 0.f;
#pragma unroll
        for (int fn = 0; fn < 2; ++fn) {
          float h0 = (mh == 0 ? acc00[fm][fn][j] : acc10[fm][fn][j]) + b1v[0][fn];
          s += fmaxf(h0, 0.f) * w2v[0][fn];
          float h1 = (mh == 0 ? acc01[fm][fn][j] : acc11[fm][fn][j]) + b1v[1][fn];
          s += fmaxf(h1, 0.f) * w2v[1][fn];
        }
        s += __shfl_xor(s, 1);
        s += __shfl_xor(s, 2);
        s += __shfl_xor(s, 4);
        s += __shfl_xor(s, 8);
        if (r16 == 0)
          red[sub_n * 256 + mh * 128 + sub_m * 64 + fm * 16 + q4 * 4 + j] = s;
      }
  __syncthreads();
  if (t < 256) {
    float p = red[t] + red[256 + t] + red[512 + t] + red[768 + t];
    part[(size_t)(m0 + t) * 8 + bn] = p;
  }
#undef STAGE
#undef LDA
#undef LDB
#undef MFMA16
#undef WAITBAR
}

// ---------------- per-batch-row: expected_k, top-k mask ----------------
// Reads the 8 per-N-tile partials directly (reduce_part folded in).
__global__ void rowstats(const float* __restrict__ part, const float* __restrict__ b2,
                         float* __restrict__ mask_out, float* __restrict__ ek_out) {
  __shared__ float vals[2048];
  __shared__ float srt[2048];
  __shared__ float redf[256];
  __shared__ int redi[256];
  int b = blockIdx.x, t = threadIdx.x;
  float b2v = b2[0];
  float psum = 0.f;
  for (int i = t; i < 2048; i += 256) {
    const float* pp = part + ((size_t)b * 2048 + i) * 8;
    float v = pp[0] + pp[1] + pp[2] + pp[3] + pp[4] + pp[5] + pp[6] + pp[7] + b2v;
    vals[i] = v; srt[i] = v;
    psum += 1.f / (1.f + expf(-v));
  }
  redf[t] = psum;
  __syncthreads();
  for (int s = 128; s > 0; s >>= 1) {
    if (t < s) redf[t] += redf[t + s];
    __syncthreads();
  }
  float ek = redf[0];
  int k = (int)ek;
  if (k < 32) k = 32;
  if (k > 2048) k = 2048;
  if (t == 0) ek_out[b] = ek;

  for (int ksz = 2; ksz <= 2048; ksz <<= 1) {
    for (int j = ksz >> 1; j > 0; j >>= 1) {
      for (int i = t; i < 2048; i += 256) {
        int ixj = i ^ j;
        if (ixj > i) {
          float a = srt[i], c = srt[ixj];
          bool up = ((i & ksz) == 0);
          if ((a > c) == up) { srt[i] = c; srt[ixj] = a; }
        }
      }
      __syncthreads();
    }
  }
  float thr = srt[2048 - k];

  int cnt = 0;
  for (int i = t; i < 2048; i += 256) cnt += (vals[i] > thr) ? 1 : 0;
  redi[t] = cnt;
  __syncthreads();
  for (int s = 128; s > 0; s >>= 1) {
    if (t < s) redi[t] += redi[t + s];
    __syncthreads();
  }
  int n_gt = redi[0];
  int need = k - n_gt;

  for (int i = t; i < 2048; i += 256) {
    float v = vals[i];
    float m = 0.f;
    if (v > thr) m = 1.f;
    else if (v == thr) {
      int pre = 0;
      for (int p = 0; p < i; ++p) pre += (vals[p] == thr) ? 1 : 0;
      if (pre < need) m = 1.f;
    }
    mask_out[(size_t)b * 2048 + i] = m;
  }
}

// ---------------- filtered = x * mask ----------------
__global__ void filter_k(const float4* __restrict__ x, const float* __restrict__ mask,
                         float4* __restrict__ out, int n4) {
  int stride = gridDim.x * blockDim.x;
  for (int i = blockIdx.x * blockDim.x + threadIdx.x; i < n4; i += stride) {
    float m = mask[i >> 9];
    float4 v = x[i];
    v.x *= m; v.y *= m; v.z *= m; v.w *= m;
    out[i] = v;
  }
}

extern "C" void kernel_launch(void* const* d_in, const int* in_sizes, int n_in,
                              void* d_out, int out_size, void* d_ws, size_t ws_size,
                              hipStream_t stream) {
  const float* x  = (const float*)d_in[0];
  const float* w1 = (const float*)d_in[1];
  const float* b1 = (const float*)d_in[2];
  const float* w2 = (const float*)d_in[3];
  const float* b2 = (const float*)d_in[4];

  float* out_filt = (float*)d_out;
  float* out_mask = out_filt + (size_t)67108864;
  float* out_ek   = out_mask + 32768;

  unsigned short* xhi = (unsigned short*)d_out;   // parked in out0 region

  char* wsb = (char*)d_ws;
  unsigned short* xlo  = (unsigned short*)wsb;                      // 134217728 B
  unsigned short* wthi = (unsigned short*)(wsb + 134217728);        // 8388608 B
  unsigned short* wtlo = (unsigned short*)(wsb + 142606336);        // 8388608 B
  float* part   = (float*)(wsb + 150994944);                        // 1048576 B used

  split_x_kernel<<<dim3(4096), dim3(256), 0, stream>>>(
      (const float4*)x, (ushort4*)xhi, (ushort4*)xlo, 16777216);
  split_wT_kernel<<<dim3(64, 64), dim3(32, 8), 0, stream>>>(w1, wthi, wtlo);
  gemm8<<<dim3(1024), dim3(512), 0, stream>>>(
      xhi, xlo, wthi, wtlo, b1, w2, part);
  rowstats<<<dim3(16), dim3(256), 0, stream>>>(part, b2, out_mask, out_ek);
  filter_k<<<dim3(4096), dim3(256), 0, stream>>>(
      (const float4*)x, out_mask, (float4*)out_filt, 16777216);
}